// Round 15
// baseline (177.886 us; speedup 1.0000x reference)
//
#include <hip/hip_runtime.h>
#include <hip/hip_bf16.h>

// Problem constants (static graph layout from the reference)
#define NG 128          // graphs
#define NPG 1024        // nodes per graph
#define NN (NG * NPG)   // 131072 nodes
#define NE (NN * 32)    // 4194304 edges
#define CH 256          // channels
#define KSEL 512        // top-k per graph

#define CAP 128         // band capacity per graph
#define EPS 0.02f       // bf16-score uncertainty band half-width

// Output layout (all float32, concatenated flat in return order)
#define OUT_X      0
#define OUT_EDGE   16777216
#define OUT_BATCH  25165824
#define OUT_PERM   25231360
#define OUT_SCORES 25296896

// Workspace layout (bytes)
#define WS_SCORES  0           // 131072 f32
#define WS_KEEP    524288      // bit-packed keep: 16 KB
#define WS_COUNTS  540672      // 1024 int
#define WS_OFFSETS 544768      // 1024 int (unused now)
#define WS_BFRAG   548864      // W1 bf16 fragment-linear: 128 KB
#define WS_BIDX    679936      // band local idx: NG*CAP int = 64 KB
#define WS_BSCORE  745472      // band fp32 scores: 64 KB
#define WS_BN      811008      // band_n: NG int
#define WS_BLO     811520      // band_lo: NG int

typedef __attribute__((ext_vector_type(8))) short bf16x8;
typedef __attribute__((ext_vector_type(4))) float f32x4;

__device__ __forceinline__ unsigned short f2bf(float f) {
    unsigned int b = __float_as_uint(f);
    return (unsigned short)((b + 0x7fffu + ((b >> 16) & 1u)) >> 16);  // RNE
}

// pack two fp32 -> one u32 of 2xbf16 via HW v_cvt_pk_bf16_f32 (RNE == f2bf)
__device__ __forceinline__ unsigned int cvt2bf(float lo, float hi) {
    union { __hip_bfloat162 h; unsigned int u; } c;
    c.h = __float22bfloat162_rn(make_float2(lo, hi));
    return c.u;
}

// fast tanh for the APPROX path only: 1 - 2/(exp(2h)+1); saturates, no NaN.
__device__ __forceinline__ float tanh_fast(float h) {
    const float e = __expf(2.0f * h);
    return 1.0f - 2.0f / (e + 1.0f);
}

// ---------- Kernel 0: pack W1 -> bf16 fragment-linear; also zero keep_bits ----------
__global__ __launch_bounds__(256)
void k_cvtW(const float* __restrict__ W1, unsigned short* __restrict__ W1b,
            unsigned int* __restrict__ keep_bits)
{
    const int t = blockIdx.x * 256 + threadIdx.x;   // 0..8191
    if (t < NN / 32) keep_bits[t] = 0u;             // 4096 words
    const int s    = t >> 10;
    const int rem  = t & 1023;
    const int n    = rem >> 6;
    const int lane = rem & 63;
    const int kbase = s * 32 + (lane >> 4) * 8;
    const int col   = n * 16 + (lane & 15);
    unsigned short u[8];
    #pragma unroll
    for (int j = 0; j < 8; ++j)
        u[j] = f2bf(W1[(size_t)(kbase + j) * CH + col]);
    uint4 v;
    v.x = u[0] | ((unsigned int)u[1] << 16);
    v.y = u[2] | ((unsigned int)u[3] << 16);
    v.z = u[4] | ((unsigned int)u[5] << 16);
    v.w = u[6] | ((unsigned int)u[7] << 16);
    *(uint4*)&W1b[(size_t)t * 8] = v;
}

// ---------- Kernel 1: approx scores via bf16 MFMA (R14 best) ----------
__global__ __launch_bounds__(256, 4)
void k_mfma_scores(const float* __restrict__ x, const unsigned short* __restrict__ W1b,
                   const float* __restrict__ b1, const float* __restrict__ W2,
                   const float* __restrict__ b2, float* __restrict__ scores)
{
    __shared__ __align__(16) short As[64 * 256];   // 32 KB row-major bf16, swizzled
    __shared__ float epi[4][64];

    const int tid = threadIdx.x;
    const int w_  = tid >> 6;
    const int l   = tid & 63;
    const int n0  = blockIdx.x * 64;

    // ---- stage x tile: fp32 coalesced read -> bf16 row-major LDS (swizzled) ----
    #pragma unroll
    for (int it = 0; it < 16; ++it) {
        const int flat = it * 1024 + tid * 4;
        const int row = flat >> 8;
        const int c   = flat & 255;            // multiple of 4
        const float4 v = *(const float4*)&x[(size_t)(n0 + row) * CH + c];
        uint2 p;
        p.x = cvt2bf(v.x, v.y);
        p.y = cvt2bf(v.z, v.w);
        const int byte = (row * 512 + c * 2) ^ ((row & 7) << 4);
        *(uint2*)((char*)As + byte) = p;
    }
    __syncthreads();

    f32x4 acc[4][4];
    #pragma unroll
    for (int m = 0; m < 4; ++m)
        #pragma unroll
        for (int n = 0; n < 4; ++n)
            acc[m][n] = (f32x4){0.f, 0.f, 0.f, 0.f};

    // B-frag double buffer (all indices compile-time per unrolled iteration)
    const unsigned short* Wl = W1b + l * 8;
    bf16x8 bc[4], bn[4];
    #pragma unroll
    for (int ni = 0; ni < 4; ++ni)
        bc[ni] = *(const bf16x8*)&Wl[(size_t)(w_ * 4 + ni) * 512];

    #pragma unroll
    for (int s = 0; s < 8; ++s) {
        if (s < 7) {
            #pragma unroll
            for (int ni = 0; ni < 4; ++ni)
                bn[ni] = *(const bf16x8*)&Wl[(size_t)((s + 1) * 16 + w_ * 4 + ni) * 512];
        }
        // A-frags: lane l -> row m*16+(l&15), k = s*32 + (l>>4)*8 + j
        bf16x8 a[4];
        #pragma unroll
        for (int m = 0; m < 4; ++m) {
            const int row  = m * 16 + (l & 15);
            const int byte = (row * 512 + s * 64 + ((l >> 4) * 16)) ^ ((l & 7) << 4);
            a[m] = *(const bf16x8*)((const char*)As + byte);
        }
        #pragma unroll
        for (int ni = 0; ni < 4; ++ni)
            #pragma unroll
            for (int m = 0; m < 4; ++m)
                acc[m][ni] = __builtin_amdgcn_mfma_f32_16x16x32_bf16(a[m], bc[ni], acc[m][ni], 0, 0, 0);
        #pragma unroll
        for (int ni = 0; ni < 4; ++ni) bc[ni] = bn[ni];
    }

    // ---- epilogue: h = acc + b1[col]; t = tanh_fast(h); row sums of t*W2 ----
    float part[16];   // [m*4 + r]: node = m*16 + (l>>4)*4 + r
    #pragma unroll
    for (int i = 0; i < 16; ++i) part[i] = 0.f;
    #pragma unroll
    for (int ni = 0; ni < 4; ++ni) {
        const int col = w_ * 64 + ni * 16 + (l & 15);
        const float b1c = b1[col];
        const float w2c = W2[col];
        #pragma unroll
        for (int m = 0; m < 4; ++m)
            #pragma unroll
            for (int r = 0; r < 4; ++r)
                part[m * 4 + r] += tanh_fast(acc[m][ni][r] + b1c) * w2c;
    }
    #pragma unroll
    for (int off = 1; off < 16; off <<= 1)
        #pragma unroll
        for (int i = 0; i < 16; ++i)
            part[i] += __shfl_xor(part[i], off, 64);

    if ((l & 15) == 0) {
        const int gq = l >> 4;
        #pragma unroll
        for (int m = 0; m < 4; ++m)
            #pragma unroll
            for (int r = 0; r < 4; ++r)
                epi[w_][m * 16 + gq * 4 + r] = part[m * 4 + r];
    }
    __syncthreads();
    if (tid < 64)
        scores[n0 + tid] = epi[0][tid] + epi[1][tid] + epi[2][tid] + epi[3][tid] + b2[0];
}

// ---------- Kernel 2: radix-select + classification + CERTAIN-ROW GATHER ----------
// After compaction, the certain slot->node map lives in LDS (reusing the dead
// radix key buffer), so this kernel also gathers x rows for certain keeps —
// k_gather's dominant part fused here (overlaps radix compute; one less launch).
__global__ __launch_bounds__(256)
void k_topk(const float* __restrict__ scores, const float* __restrict__ x,
            float* __restrict__ out, unsigned int* __restrict__ keep_bits,
            int* __restrict__ band_idx, int* __restrict__ band_n, int* __restrict__ band_lo)
{
    __shared__ float    sf[1024];
    __shared__ unsigned uk[1024];   // radix keys, then reused as slot->node map
    __shared__ int      hist[256];
    __shared__ int      cge[256];
    __shared__ unsigned s_prefix;
    __shared__ int      s_rank;
    __shared__ int      wtot[4];

    const int g = blockIdx.x;
    const int t = threadIdx.x;

    #pragma unroll
    for (int h = 0; h < 4; ++h) {
        const int i = h * 256 + t;
        const float f = scores[g * NPG + i];
        sf[i] = f;
        const unsigned b = __float_as_uint(f);
        uk[i] = (b & 0x80000000u) ? ~b : (b | 0x80000000u);   // monotone: bigger u = bigger f
    }
    if (t == 0) { s_prefix = 0u; s_rank = KSEL; }
    __syncthreads();

    const unsigned pmaskv[4] = {0u, 0xFF000000u, 0xFFFF0000u, 0xFFFFFF00u};
    #pragma unroll
    for (int pass = 0; pass < 4; ++pass) {
        const int shift = 24 - pass * 8;
        hist[t] = 0;
        __syncthreads();
        const unsigned pm  = pmaskv[pass];
        const unsigned pfx = s_prefix;
        #pragma unroll
        for (int h = 0; h < 4; ++h) {
            const unsigned u = uk[h * 256 + t];
            if ((u & pm) == pfx) atomicAdd(&hist[(u >> shift) & 255], 1);
        }
        __syncthreads();
        cge[t] = hist[t];
        __syncthreads();
        #pragma unroll
        for (int off = 1; off < 256; off <<= 1) {        // suffix sums: cge[b] = #(byte >= b)
            const int v = (t + off < 256) ? cge[t + off] : 0;
            __syncthreads();
            cge[t] += v;
            __syncthreads();
        }
        const int r = s_rank;
        const int above = (t == 255) ? 0 : cge[t + 1];
        if (cge[t] >= r && above < r) {                  // exactly one thread matches
            s_prefix = pfx | ((unsigned)t << shift);
            s_rank   = r - above;
        }
        __syncthreads();
    }

    const unsigned u512 = s_prefix;                      // full rank-512 key
    const unsigned fb = (u512 & 0x80000000u) ? (u512 & 0x7FFFFFFFu) : ~u512;
    const float tau = __uint_as_float(fb);

    // deterministic classification + stable compaction (node li = t*4+j)
    bool cert[4], bnd[4];
    int myc = 0, myb = 0;
    #pragma unroll
    for (int j = 0; j < 4; ++j) {
        const float f = sf[t * 4 + j];
        cert[j] = (f > tau + EPS);
        bnd[j]  = (!cert[j]) && (f >= tau - EPS);
        myc += cert[j] ? 1 : 0;
        myb += bnd[j] ? 1 : 0;
    }
    const int pack = (myc << 16) | myb;
    const int lane = t & 63, w = t >> 6;
    int incl = pack;
    #pragma unroll
    for (int off = 1; off < 64; off <<= 1) {
        const int v = __shfl_up(incl, off, 64);
        if (lane >= off) incl += v;
    }
    if (lane == 63) wtot[w] = incl;
    __syncthreads();   // also: all radix reads of uk[] complete before map reuse
    int wbase = 0;
    for (int i = 0; i < w; ++i) wbase += wtot[i];
    const int excl = wbase + incl - pack;
    int cpos = excl >> 16;
    int bpos = excl & 0xFFFF;
    const int total = wtot[0] + wtot[1] + wtot[2] + wtot[3];
    const int lo_cnt = total >> 16;

    int* cmap = (int*)uk;   // slot -> local node, certain keeps
    #pragma unroll
    for (int j = 0; j < 4; ++j) {
        const int li = t * 4 + j;
        if (cert[j]) {
            const int gi = g * NPG + li;
            out[OUT_PERM   + g * KSEL + cpos] = (float)gi;
            out[OUT_SCORES + g * KSEL + cpos] = sf[li];
            cmap[cpos] = li;
            atomicOr(&keep_bits[gi >> 5], 1u << (gi & 31));
            ++cpos;
        } else if (bnd[j]) {
            if (bpos < CAP) band_idx[g * CAP + bpos] = li;
            ++bpos;
        }
    }
    out[OUT_BATCH + g * KSEL + t]       = (float)g;
    out[OUT_BATCH + g * KSEL + t + 256] = (float)g;
    if (t == 0) {
        band_lo[g] = lo_cnt;
        band_n[g]  = min(total & 0xFFFF, CAP);
    }
    __syncthreads();   // cmap complete

    // ---- fused gather of certain rows: wave w handles slots w, w+4, ... ----
    for (int slot = w; slot < lo_cnt; slot += 4) {
        const int li = cmap[slot];
        const float4* src = (const float4*)&x[((size_t)g * NPG + li) * CH];
        float4* dst = (float4*)&out[OUT_X + (size_t)(g * KSEL + slot) * CH];
        dst[lane] = src[lane];
    }
}

// ---------- Kernel 3: exact fp32 rescore of band nodes (R11 block version) ----------
__global__ __launch_bounds__(256, 2)
void k_rescore(const float* __restrict__ x, const float* __restrict__ W1,
               const float* __restrict__ b1, const float* __restrict__ W2,
               const float* __restrict__ b2, const int* __restrict__ band_idx,
               const int* __restrict__ band_n, float* __restrict__ band_scores)
{
    const int g = blockIdx.x >> 2;
    const int c0 = (blockIdx.x & 3) * 32;
    if (band_n[g] <= c0) return;   // uniform early-exit (no barriers crossed)

    __shared__ __align__(16) float W1s[16][CH];
    __shared__ __align__(16) float Xs[32][16];

    const int tid = threadIdx.x;
    const int w_  = tid >> 6;
    const int l   = tid & 63;

    int iv = 0;
    if (w_ < 2) iv = band_idx[g * CAP + c0 + w_ * 16 + (l >> 2)] & 1023;
    const float* xg = x + ((size_t)g * NPG + iv) * CH;

    const float4 b1v = *(const float4*)&b1[l * 4];
    float acc[8][4];
    #pragma unroll
    for (int n = 0; n < 8; ++n) {
        acc[n][0] = b1v.x; acc[n][1] = b1v.y; acc[n][2] = b1v.z; acc[n][3] = b1v.w;
    }

    for (int kc = 0; kc < 16; ++kc) {
        __syncthreads();
        #pragma unroll
        for (int it = 0; it < 4; ++it) {
            const float* gp = W1 + (size_t)kc * (16 * CH) + (w_ * 4 + it) * CH + l * 4;
            float* lb = &W1s[0][0] + (w_ * 4 + it) * CH;
            __builtin_amdgcn_global_load_lds(
                (const __attribute__((address_space(1))) void*)gp,
                (__attribute__((address_space(3))) void*)lb, 16, 0, 0);
        }
        if (w_ < 2) {
            const float* gp = xg + kc * 16 + (l & 3) * 4;
            float* lb = &Xs[0][0] + w_ * 256;
            __builtin_amdgcn_global_load_lds(
                (const __attribute__((address_space(1))) void*)gp,
                (__attribute__((address_space(3))) void*)lb, 16, 0, 0);
        }
        __syncthreads();

        #pragma unroll
        for (int kq = 0; kq < 4; ++kq) {
            const int k4 = kq * 4;
            const float4 wv0 = *(const float4*)&W1s[k4 + 0][l * 4];
            const float4 wv1 = *(const float4*)&W1s[k4 + 1][l * 4];
            const float4 wv2 = *(const float4*)&W1s[k4 + 2][l * 4];
            const float4 wv3 = *(const float4*)&W1s[k4 + 3][l * 4];
            #pragma unroll
            for (int n = 0; n < 8; ++n) {
                const float4 xv = *(const float4*)&Xs[w_ * 8 + n][k4];
                acc[n][0] = fmaf(xv.x, wv0.x, acc[n][0]);
                acc[n][1] = fmaf(xv.x, wv0.y, acc[n][1]);
                acc[n][2] = fmaf(xv.x, wv0.z, acc[n][2]);
                acc[n][3] = fmaf(xv.x, wv0.w, acc[n][3]);
                acc[n][0] = fmaf(xv.y, wv1.x, acc[n][0]);
                acc[n][1] = fmaf(xv.y, wv1.y, acc[n][1]);
                acc[n][2] = fmaf(xv.y, wv1.z, acc[n][2]);
                acc[n][3] = fmaf(xv.y, wv1.w, acc[n][3]);
                acc[n][0] = fmaf(xv.z, wv2.x, acc[n][0]);
                acc[n][1] = fmaf(xv.z, wv2.y, acc[n][1]);
                acc[n][2] = fmaf(xv.z, wv2.z, acc[n][2]);
                acc[n][3] = fmaf(xv.z, wv2.w, acc[n][3]);
                acc[n][0] = fmaf(xv.w, wv3.x, acc[n][0]);
                acc[n][1] = fmaf(xv.w, wv3.y, acc[n][1]);
                acc[n][2] = fmaf(xv.w, wv3.z, acc[n][2]);
                acc[n][3] = fmaf(xv.w, wv3.w, acc[n][3]);
            }
        }
    }

    const float4 w2v = *(const float4*)&W2[l * 4];
    const float  bb  = b2[0];
    float s_[8];
    #pragma unroll
    for (int n = 0; n < 8; ++n) {
        s_[n] = tanhf(acc[n][0]) * w2v.x + tanhf(acc[n][1]) * w2v.y
              + tanhf(acc[n][2]) * w2v.z + tanhf(acc[n][3]) * w2v.w;
    }
    #pragma unroll
    for (int off = 1; off < 64; off <<= 1)
        #pragma unroll
        for (int n = 0; n < 8; ++n)
            s_[n] += __shfl_xor(s_[n], off, 64);

    if (l == 0) {
        #pragma unroll
        for (int n = 0; n < 8; ++n)
            band_scores[g * CAP + c0 + w_ * 8 + n] = s_[n] + bb;
    }
}

// ---------- Kernel 4: band selection + fused band-row gather ----------
__global__ __launch_bounds__(64)
void k_bandsel(const float* __restrict__ band_scores, const int* __restrict__ band_idx,
               const int* __restrict__ band_n, const int* __restrict__ band_lo,
               const float* __restrict__ x, float* __restrict__ out,
               unsigned int* __restrict__ keep_bits)
{
    __shared__ float bs[CAP];
    __shared__ int   bi[CAP];
    const int g = blockIdx.x;
    const int t = threadIdx.x;
    const int n  = band_n[g];
    const int lo = band_lo[g];
    int needed = KSEL - lo;
    if (needed > n) needed = n;

    #pragma unroll
    for (int h = 0; h < 2; ++h) {
        const int q = t + h * 64;
        const bool valid = q < n;
        bs[q] = valid ? band_scores[g * CAP + q] : -3.402823466e+38f;
        bi[q] = valid ? band_idx[g * CAP + q] : (NPG + q);
    }
    __syncthreads();
    for (int size = 2; size <= CAP; size <<= 1) {
        for (int stride = size >> 1; stride > 0; stride >>= 1) {
            __syncthreads();
            const int lo_i = ((t & ~(stride - 1)) << 1) | (t & (stride - 1));
            const int hi_i = lo_i + stride;
            const bool dirDesc = ((lo_i & size) == 0);
            const float va = bs[lo_i], vb = bs[hi_i];
            const int ia = bi[lo_i], ib = bi[hi_i];
            const bool aB = (va > vb) || (va == vb && ia < ib);
            if (aB != dirDesc) {
                bs[lo_i] = vb; bs[hi_i] = va;
                bi[lo_i] = ib; bi[hi_i] = ia;
            }
        }
    }
    __syncthreads();
    #pragma unroll
    for (int h = 0; h < 2; ++h) {
        const int s = t + h * 64;
        if (s < needed) {
            const int li = bi[s];
            const int gi = g * NPG + li;
            out[OUT_PERM   + g * KSEL + lo + s] = (float)gi;
            out[OUT_SCORES + g * KSEL + lo + s] = bs[s];
            atomicOr(&keep_bits[gi >> 5], 1u << (gi & 31));
        }
    }
    // fused gather of the selected band rows (one row per iteration, 64 lanes)
    for (int s = 0; s < needed; ++s) {
        const int li = bi[s] & 1023;
        const float4* src = (const float4*)&x[((size_t)g * NPG + li) * CH];
        float4* dst = (float4*)&out[OUT_X + (size_t)(g * KSEL + lo + s) * CH];
        dst[t] = src[t];
    }
}

// ---------- Kernel 5: per-block kept-edge counts + fill our -1 slab ----------
__global__ __launch_bounds__(256)
void k_edgecount(const int* __restrict__ ei, const unsigned int* __restrict__ keep_bits,
                 int* __restrict__ counts, float* __restrict__ out_edge)
{
    const int t = threadIdx.x;
    const float4 neg = make_float4(-1.f, -1.f, -1.f, -1.f);
    #pragma unroll
    for (int q = 0; q < 4; ++q) {
        ((float4*)out_edge)[(size_t)blockIdx.x * 1024 + q * 256 + t] = neg;
        ((float4*)(out_edge + NE))[(size_t)blockIdx.x * 1024 + q * 256 + t] = neg;
    }

    const size_t base = (size_t)blockIdx.x * 4096 + (size_t)t * 16;
    const int* rowp = ei;
    const int* colp = ei + NE;
    int rv[16], cv[16];
    #pragma unroll
    for (int q = 0; q < 4; ++q) {
        int4 r4 = *(const int4*)&rowp[base + q * 4];
        int4 c4 = *(const int4*)&colp[base + q * 4];
        rv[q*4+0]=r4.x; rv[q*4+1]=r4.y; rv[q*4+2]=r4.z; rv[q*4+3]=r4.w;
        cv[q*4+0]=c4.x; cv[q*4+1]=c4.y; cv[q*4+2]=c4.z; cv[q*4+3]=c4.w;
    }
    int cnt = 0;
    #pragma unroll
    for (int q = 0; q < 16; ++q)
        cnt += (int)((keep_bits[rv[q] >> 5] >> (rv[q] & 31)) &
                     (keep_bits[cv[q] >> 5] >> (cv[q] & 31)) & 1u);

    #pragma unroll
    for (int off = 1; off < 64; off <<= 1) cnt += __shfl_xor(cnt, off, 64);
    __shared__ int wsum[4];
    if ((t & 63) == 0) wsum[t >> 6] = cnt;
    __syncthreads();
    if (t == 0) counts[blockIdx.x] = wsum[0] + wsum[1] + wsum[2] + wsum[3];
}

// ---------- Kernel 6: stable scatter of kept edges (scan fused in) ----------
__global__ __launch_bounds__(256)
void k_scatter(const int* __restrict__ ei, const unsigned int* __restrict__ keep_bits,
               const int* __restrict__ counts, float* __restrict__ out_edge)
{
    const int t = threadIdx.x;
    const int lane = t & 63, w = t >> 6;

    // inline exclusive scan: base = sum(counts[0..bid)) — counts is 4 KB, L2-hot
    int pre = 0;
    for (int i = t; i < blockIdx.x; i += 256) pre += counts[i];
    #pragma unroll
    for (int off = 1; off < 64; off <<= 1) pre += __shfl_xor(pre, off, 64);
    __shared__ int wpre[4];
    if (lane == 0) wpre[w] = pre;

    const size_t base = (size_t)blockIdx.x * 4096 + (size_t)t * 16;
    const int* rowp = ei;
    const int* colp = ei + NE;
    int rv[16], cv[16];
    #pragma unroll
    for (int q = 0; q < 4; ++q) {
        int4 r4 = *(const int4*)&rowp[base + q * 4];
        int4 c4 = *(const int4*)&colp[base + q * 4];
        rv[q*4+0]=r4.x; rv[q*4+1]=r4.y; rv[q*4+2]=r4.z; rv[q*4+3]=r4.w;
        cv[q*4+0]=c4.x; cv[q*4+1]=c4.y; cv[q*4+2]=c4.z; cv[q*4+3]=c4.w;
    }
    unsigned m = 0; int cnt = 0;
    #pragma unroll
    for (int q = 0; q < 16; ++q) {
        const bool kk = ((keep_bits[rv[q] >> 5] >> (rv[q] & 31)) &
                         (keep_bits[cv[q] >> 5] >> (cv[q] & 31)) & 1u) != 0u;
        m |= ((unsigned)kk) << q;
        cnt += (int)kk;
    }
    int incl = cnt;
    #pragma unroll
    for (int off = 1; off < 64; off <<= 1) {
        int v = __shfl_up(incl, off, 64);
        if (lane >= off) incl += v;
    }
    __shared__ int wtot[4];
    if (lane == 63) wtot[w] = incl;
    __syncthreads();
    const int blk_base = wpre[0] + wpre[1] + wpre[2] + wpre[3];
    int wbase = 0;
    for (int i = 0; i < w; ++i) wbase += wtot[i];
    int pos = blk_base + wbase + (incl - cnt);
    #pragma unroll
    for (int q = 0; q < 16; ++q) {
        if (m & (1u << q)) {
            out_edge[pos]      = (float)rv[q];
            out_edge[NE + pos] = (float)cv[q];
            ++pos;
        }
    }
}

extern "C" void kernel_launch(void* const* d_in, const int* in_sizes, int n_in,
                              void* d_out, int out_size, void* d_ws, size_t ws_size,
                              hipStream_t stream)
{
    const float* x  = (const float*)d_in[0];
    const int*   ei = (const int*)d_in[1];
    const float* W1 = (const float*)d_in[3];
    const float* b1 = (const float*)d_in[4];
    const float* W2 = (const float*)d_in[5];
    const float* b2 = (const float*)d_in[6];

    float* out = (float*)d_out;
    char*  ws  = (char*)d_ws;
    float*          scores    = (float*)(ws + WS_SCORES);
    unsigned int*   keep_bits = (unsigned int*)(ws + WS_KEEP);
    int*            counts    = (int*)(ws + WS_COUNTS);
    unsigned short* W1b       = (unsigned short*)(ws + WS_BFRAG);
    int*            band_idx  = (int*)(ws + WS_BIDX);
    float*          band_sc   = (float*)(ws + WS_BSCORE);
    int*            band_n    = (int*)(ws + WS_BN);
    int*            band_lo   = (int*)(ws + WS_BLO);

    k_cvtW<<<32, 256, 0, stream>>>(W1, W1b, keep_bits);
    k_mfma_scores<<<NN / 64, 256, 0, stream>>>(x, W1b, b1, W2, b2, scores);
    k_topk<<<NG, 256, 0, stream>>>(scores, x, out, keep_bits, band_idx, band_n, band_lo);
    k_rescore<<<NG * (CAP / 32), 256, 0, stream>>>(x, W1, b1, W2, b2, band_idx, band_n, band_sc);
    k_bandsel<<<NG, 64, 0, stream>>>(band_sc, band_idx, band_n, band_lo, x, out, keep_bits);
    k_edgecount<<<NE / 4096, 256, 0, stream>>>(ei, keep_bits, counts, out + OUT_EDGE);
    k_scatter<<<NE / 4096, 256, 0, stream>>>(ei, keep_bits, counts, out + OUT_EDGE);
}

// Round 16
// 156.861 us; speedup vs baseline: 1.1340x; 1.1340x over previous
//
#include <hip/hip_runtime.h>
#include <hip/hip_bf16.h>

// Problem constants (static graph layout from the reference)
#define NG 128          // graphs
#define NPG 1024        // nodes per graph
#define NN (NG * NPG)   // 131072 nodes
#define NE (NN * 32)    // 4194304 edges
#define CH 256          // channels
#define KSEL 512        // top-k per graph

#define CAP 128         // band capacity per graph
#define EPS 0.02f       // bf16-score uncertainty band half-width

// Output layout (all float32, concatenated flat in return order)
#define OUT_X      0
#define OUT_EDGE   16777216
#define OUT_BATCH  25165824
#define OUT_PERM   25231360
#define OUT_SCORES 25296896

// Workspace layout (bytes)
#define WS_SCORES  0           // 131072 f32
#define WS_KEEP    524288      // bit-packed keep: 16 KB
#define WS_COUNTS  540672      // 1024 int
#define WS_BFRAG   548864      // W1 bf16 fragment-linear: 128 KB
#define WS_BIDX    679936      // band local idx: NG*CAP int = 64 KB
#define WS_BSCORE  745472      // band fp32 scores: 64 KB
#define WS_BN      811008      // band_n: NG int
#define WS_BLO     811520      // band_lo: NG int

typedef __attribute__((ext_vector_type(8))) short bf16x8;
typedef __attribute__((ext_vector_type(4))) float f32x4;

__device__ __forceinline__ unsigned short f2bf(float f) {
    unsigned int b = __float_as_uint(f);
    return (unsigned short)((b + 0x7fffu + ((b >> 16) & 1u)) >> 16);  // RNE
}

// pack two fp32 -> one u32 of 2xbf16 via HW v_cvt_pk_bf16_f32 (RNE == f2bf)
__device__ __forceinline__ unsigned int cvt2bf(float lo, float hi) {
    union { __hip_bfloat162 h; unsigned int u; } c;
    c.h = __float22bfloat162_rn(make_float2(lo, hi));
    return c.u;
}

// fast tanh for the APPROX path only: 1 - 2/(exp(2h)+1); saturates, no NaN.
__device__ __forceinline__ float tanh_fast(float h) {
    const float e = __expf(2.0f * h);
    return 1.0f - 2.0f / (e + 1.0f);
}

// ---------- Kernel 0: pack W1 -> bf16 fragment-linear; also zero keep_bits ----------
__global__ __launch_bounds__(256)
void k_cvtW(const float* __restrict__ W1, unsigned short* __restrict__ W1b,
            unsigned int* __restrict__ keep_bits)
{
    const int t = blockIdx.x * 256 + threadIdx.x;   // 0..8191
    if (t < NN / 32) keep_bits[t] = 0u;             // 4096 words
    const int s    = t >> 10;
    const int rem  = t & 1023;
    const int n    = rem >> 6;
    const int lane = rem & 63;
    const int kbase = s * 32 + (lane >> 4) * 8;
    const int col   = n * 16 + (lane & 15);
    unsigned short u[8];
    #pragma unroll
    for (int j = 0; j < 8; ++j)
        u[j] = f2bf(W1[(size_t)(kbase + j) * CH + col]);
    uint4 v;
    v.x = u[0] | ((unsigned int)u[1] << 16);
    v.y = u[2] | ((unsigned int)u[3] << 16);
    v.z = u[4] | ((unsigned int)u[5] << 16);
    v.w = u[6] | ((unsigned int)u[7] << 16);
    *(uint4*)&W1b[(size_t)t * 8] = v;
}

// ---------- Kernel 1: approx scores via bf16 MFMA (R14 best) ----------
__global__ __launch_bounds__(256, 4)
void k_mfma_scores(const float* __restrict__ x, const unsigned short* __restrict__ W1b,
                   const float* __restrict__ b1, const float* __restrict__ W2,
                   const float* __restrict__ b2, float* __restrict__ scores)
{
    __shared__ __align__(16) short As[64 * 256];   // 32 KB row-major bf16, swizzled
    __shared__ float epi[4][64];

    const int tid = threadIdx.x;
    const int w_  = tid >> 6;
    const int l   = tid & 63;
    const int n0  = blockIdx.x * 64;

    // ---- stage x tile: fp32 coalesced read -> bf16 row-major LDS (swizzled) ----
    #pragma unroll
    for (int it = 0; it < 16; ++it) {
        const int flat = it * 1024 + tid * 4;
        const int row = flat >> 8;
        const int c   = flat & 255;            // multiple of 4
        const float4 v = *(const float4*)&x[(size_t)(n0 + row) * CH + c];
        uint2 p;
        p.x = cvt2bf(v.x, v.y);
        p.y = cvt2bf(v.z, v.w);
        const int byte = (row * 512 + c * 2) ^ ((row & 7) << 4);
        *(uint2*)((char*)As + byte) = p;
    }
    __syncthreads();

    f32x4 acc[4][4];
    #pragma unroll
    for (int m = 0; m < 4; ++m)
        #pragma unroll
        for (int n = 0; n < 4; ++n)
            acc[m][n] = (f32x4){0.f, 0.f, 0.f, 0.f};

    // B-frag double buffer (all indices compile-time per unrolled iteration)
    const unsigned short* Wl = W1b + l * 8;
    bf16x8 bc[4], bn[4];
    #pragma unroll
    for (int ni = 0; ni < 4; ++ni)
        bc[ni] = *(const bf16x8*)&Wl[(size_t)(w_ * 4 + ni) * 512];

    #pragma unroll
    for (int s = 0; s < 8; ++s) {
        if (s < 7) {
            #pragma unroll
            for (int ni = 0; ni < 4; ++ni)
                bn[ni] = *(const bf16x8*)&Wl[(size_t)((s + 1) * 16 + w_ * 4 + ni) * 512];
        }
        // A-frags: lane l -> row m*16+(l&15), k = s*32 + (l>>4)*8 + j
        bf16x8 a[4];
        #pragma unroll
        for (int m = 0; m < 4; ++m) {
            const int row  = m * 16 + (l & 15);
            const int byte = (row * 512 + s * 64 + ((l >> 4) * 16)) ^ ((l & 7) << 4);
            a[m] = *(const bf16x8*)((const char*)As + byte);
        }
        #pragma unroll
        for (int ni = 0; ni < 4; ++ni)
            #pragma unroll
            for (int m = 0; m < 4; ++m)
                acc[m][ni] = __builtin_amdgcn_mfma_f32_16x16x32_bf16(a[m], bc[ni], acc[m][ni], 0, 0, 0);
        #pragma unroll
        for (int ni = 0; ni < 4; ++ni) bc[ni] = bn[ni];
    }

    // ---- epilogue: h = acc + b1[col]; t = tanh_fast(h); row sums of t*W2 ----
    float part[16];   // [m*4 + r]: node = m*16 + (l>>4)*4 + r
    #pragma unroll
    for (int i = 0; i < 16; ++i) part[i] = 0.f;
    #pragma unroll
    for (int ni = 0; ni < 4; ++ni) {
        const int col = w_ * 64 + ni * 16 + (l & 15);
        const float b1c = b1[col];
        const float w2c = W2[col];
        #pragma unroll
        for (int m = 0; m < 4; ++m)
            #pragma unroll
            for (int r = 0; r < 4; ++r)
                part[m * 4 + r] += tanh_fast(acc[m][ni][r] + b1c) * w2c;
    }
    #pragma unroll
    for (int off = 1; off < 16; off <<= 1)
        #pragma unroll
        for (int i = 0; i < 16; ++i)
            part[i] += __shfl_xor(part[i], off, 64);

    if ((l & 15) == 0) {
        const int gq = l >> 4;
        #pragma unroll
        for (int m = 0; m < 4; ++m)
            #pragma unroll
            for (int r = 0; r < 4; ++r)
                epi[w_][m * 16 + gq * 4 + r] = part[m * 4 + r];
    }
    __syncthreads();
    if (tid < 64)
        scores[n0 + tid] = epi[0][tid] + epi[1][tid] + epi[2][tid] + epi[3][tid] + b2[0];
}

// ---------- Kernel 2: radix-select top-512 threshold + certain/band classification ----------
__global__ __launch_bounds__(256)
void k_topk(const float* __restrict__ scores, float* __restrict__ out,
            unsigned int* __restrict__ keep_bits, int* __restrict__ band_idx,
            int* __restrict__ band_n, int* __restrict__ band_lo)
{
    __shared__ float    sf[1024];
    __shared__ unsigned uk[1024];
    __shared__ int      hist[256];
    __shared__ int      cge[256];
    __shared__ unsigned s_prefix;
    __shared__ int      s_rank;
    __shared__ int      wtot[4];

    const int g = blockIdx.x;
    const int t = threadIdx.x;

    #pragma unroll
    for (int h = 0; h < 4; ++h) {
        const int i = h * 256 + t;
        const float f = scores[g * NPG + i];
        sf[i] = f;
        const unsigned b = __float_as_uint(f);
        uk[i] = (b & 0x80000000u) ? ~b : (b | 0x80000000u);   // monotone: bigger u = bigger f
    }
    if (t == 0) { s_prefix = 0u; s_rank = KSEL; }
    __syncthreads();

    const unsigned pmaskv[4] = {0u, 0xFF000000u, 0xFFFF0000u, 0xFFFFFF00u};
    #pragma unroll
    for (int pass = 0; pass < 4; ++pass) {
        const int shift = 24 - pass * 8;
        hist[t] = 0;
        __syncthreads();
        const unsigned pm  = pmaskv[pass];
        const unsigned pfx = s_prefix;
        #pragma unroll
        for (int h = 0; h < 4; ++h) {
            const unsigned u = uk[h * 256 + t];
            if ((u & pm) == pfx) atomicAdd(&hist[(u >> shift) & 255], 1);
        }
        __syncthreads();
        cge[t] = hist[t];
        __syncthreads();
        #pragma unroll
        for (int off = 1; off < 256; off <<= 1) {        // suffix sums: cge[b] = #(byte >= b)
            const int v = (t + off < 256) ? cge[t + off] : 0;
            __syncthreads();
            cge[t] += v;
            __syncthreads();
        }
        const int r = s_rank;
        const int above = (t == 255) ? 0 : cge[t + 1];
        if (cge[t] >= r && above < r) {                  // exactly one thread matches
            s_prefix = pfx | ((unsigned)t << shift);
            s_rank   = r - above;
        }
        __syncthreads();
    }

    const unsigned u512 = s_prefix;                      // full rank-512 key
    const unsigned fb = (u512 & 0x80000000u) ? (u512 & 0x7FFFFFFFu) : ~u512;
    const float tau = __uint_as_float(fb);

    // deterministic classification + stable compaction (node li = t*4+j)
    bool cert[4], bnd[4];
    int myc = 0, myb = 0;
    #pragma unroll
    for (int j = 0; j < 4; ++j) {
        const float f = sf[t * 4 + j];
        cert[j] = (f > tau + EPS);
        bnd[j]  = (!cert[j]) && (f >= tau - EPS);
        myc += cert[j] ? 1 : 0;
        myb += bnd[j] ? 1 : 0;
    }
    const int pack = (myc << 16) | myb;
    const int lane = t & 63, w = t >> 6;
    int incl = pack;
    #pragma unroll
    for (int off = 1; off < 64; off <<= 1) {
        const int v = __shfl_up(incl, off, 64);
        if (lane >= off) incl += v;
    }
    if (lane == 63) wtot[w] = incl;
    __syncthreads();
    int wbase = 0;
    for (int i = 0; i < w; ++i) wbase += wtot[i];
    const int excl = wbase + incl - pack;
    int cpos = excl >> 16;
    int bpos = excl & 0xFFFF;
    const int total = wtot[0] + wtot[1] + wtot[2] + wtot[3];

    #pragma unroll
    for (int j = 0; j < 4; ++j) {
        const int li = t * 4 + j;
        if (cert[j]) {
            const int gi = g * NPG + li;
            out[OUT_PERM   + g * KSEL + cpos] = (float)gi;
            out[OUT_SCORES + g * KSEL + cpos] = sf[li];
            atomicOr(&keep_bits[gi >> 5], 1u << (gi & 31));
            ++cpos;
        } else if (bnd[j]) {
            if (bpos < CAP) band_idx[g * CAP + bpos] = li;
            ++bpos;
        }
    }
    out[OUT_BATCH + g * KSEL + t]       = (float)g;
    out[OUT_BATCH + g * KSEL + t + 256] = (float)g;
    if (t == 0) {
        band_lo[g] = (total >> 16);
        band_n[g]  = min(total & 0xFFFF, CAP);
    }
}

// ---------- Kernel 3: exact fp32 rescore of band nodes (R11 block version) ----------
__global__ __launch_bounds__(256, 2)
void k_rescore(const float* __restrict__ x, const float* __restrict__ W1,
               const float* __restrict__ b1, const float* __restrict__ W2,
               const float* __restrict__ b2, const int* __restrict__ band_idx,
               const int* __restrict__ band_n, float* __restrict__ band_scores)
{
    const int g = blockIdx.x >> 2;
    const int c0 = (blockIdx.x & 3) * 32;
    if (band_n[g] <= c0) return;   // uniform early-exit (no barriers crossed)

    __shared__ __align__(16) float W1s[16][CH];
    __shared__ __align__(16) float Xs[32][16];

    const int tid = threadIdx.x;
    const int w_  = tid >> 6;
    const int l   = tid & 63;

    int iv = 0;
    if (w_ < 2) iv = band_idx[g * CAP + c0 + w_ * 16 + (l >> 2)] & 1023;
    const float* xg = x + ((size_t)g * NPG + iv) * CH;

    const float4 b1v = *(const float4*)&b1[l * 4];
    float acc[8][4];
    #pragma unroll
    for (int n = 0; n < 8; ++n) {
        acc[n][0] = b1v.x; acc[n][1] = b1v.y; acc[n][2] = b1v.z; acc[n][3] = b1v.w;
    }

    for (int kc = 0; kc < 16; ++kc) {
        __syncthreads();
        #pragma unroll
        for (int it = 0; it < 4; ++it) {
            const float* gp = W1 + (size_t)kc * (16 * CH) + (w_ * 4 + it) * CH + l * 4;
            float* lb = &W1s[0][0] + (w_ * 4 + it) * CH;
            __builtin_amdgcn_global_load_lds(
                (const __attribute__((address_space(1))) void*)gp,
                (__attribute__((address_space(3))) void*)lb, 16, 0, 0);
        }
        if (w_ < 2) {
            const float* gp = xg + kc * 16 + (l & 3) * 4;
            float* lb = &Xs[0][0] + w_ * 256;
            __builtin_amdgcn_global_load_lds(
                (const __attribute__((address_space(1))) void*)gp,
                (__attribute__((address_space(3))) void*)lb, 16, 0, 0);
        }
        __syncthreads();

        #pragma unroll
        for (int kq = 0; kq < 4; ++kq) {
            const int k4 = kq * 4;
            const float4 wv0 = *(const float4*)&W1s[k4 + 0][l * 4];
            const float4 wv1 = *(const float4*)&W1s[k4 + 1][l * 4];
            const float4 wv2 = *(const float4*)&W1s[k4 + 2][l * 4];
            const float4 wv3 = *(const float4*)&W1s[k4 + 3][l * 4];
            #pragma unroll
            for (int n = 0; n < 8; ++n) {
                const float4 xv = *(const float4*)&Xs[w_ * 8 + n][k4];
                acc[n][0] = fmaf(xv.x, wv0.x, acc[n][0]);
                acc[n][1] = fmaf(xv.x, wv0.y, acc[n][1]);
                acc[n][2] = fmaf(xv.x, wv0.z, acc[n][2]);
                acc[n][3] = fmaf(xv.x, wv0.w, acc[n][3]);
                acc[n][0] = fmaf(xv.y, wv1.x, acc[n][0]);
                acc[n][1] = fmaf(xv.y, wv1.y, acc[n][1]);
                acc[n][2] = fmaf(xv.y, wv1.z, acc[n][2]);
                acc[n][3] = fmaf(xv.y, wv1.w, acc[n][3]);
                acc[n][0] = fmaf(xv.z, wv2.x, acc[n][0]);
                acc[n][1] = fmaf(xv.z, wv2.y, acc[n][1]);
                acc[n][2] = fmaf(xv.z, wv2.z, acc[n][2]);
                acc[n][3] = fmaf(xv.z, wv2.w, acc[n][3]);
                acc[n][0] = fmaf(xv.w, wv3.x, acc[n][0]);
                acc[n][1] = fmaf(xv.w, wv3.y, acc[n][1]);
                acc[n][2] = fmaf(xv.w, wv3.z, acc[n][2]);
                acc[n][3] = fmaf(xv.w, wv3.w, acc[n][3]);
            }
        }
    }

    const float4 w2v = *(const float4*)&W2[l * 4];
    const float  bb  = b2[0];
    float s_[8];
    #pragma unroll
    for (int n = 0; n < 8; ++n) {
        s_[n] = tanhf(acc[n][0]) * w2v.x + tanhf(acc[n][1]) * w2v.y
              + tanhf(acc[n][2]) * w2v.z + tanhf(acc[n][3]) * w2v.w;
    }
    #pragma unroll
    for (int off = 1; off < 64; off <<= 1)
        #pragma unroll
        for (int n = 0; n < 8; ++n)
            s_[n] += __shfl_xor(s_[n], off, 64);

    if (l == 0) {
        #pragma unroll
        for (int n = 0; n < 8; ++n)
            band_scores[g * CAP + c0 + w_ * 8 + n] = s_[n] + bb;
    }
}

// ---------- Kernel 4: select top-(512-lo) of band by fp32 score ----------
__global__ __launch_bounds__(64)
void k_bandsel(const float* __restrict__ band_scores, const int* __restrict__ band_idx,
               const int* __restrict__ band_n, const int* __restrict__ band_lo,
               float* __restrict__ out, unsigned int* __restrict__ keep_bits)
{
    __shared__ float bs[CAP];
    __shared__ int   bi[CAP];
    const int g = blockIdx.x;
    const int t = threadIdx.x;
    const int n  = band_n[g];
    const int lo = band_lo[g];
    int needed = KSEL - lo;
    if (needed > n) needed = n;

    #pragma unroll
    for (int h = 0; h < 2; ++h) {
        const int q = t + h * 64;
        const bool valid = q < n;
        bs[q] = valid ? band_scores[g * CAP + q] : -3.402823466e+38f;
        bi[q] = valid ? band_idx[g * CAP + q] : (NPG + q);
    }
    __syncthreads();
    for (int size = 2; size <= CAP; size <<= 1) {
        for (int stride = size >> 1; stride > 0; stride >>= 1) {
            __syncthreads();
            const int lo_i = ((t & ~(stride - 1)) << 1) | (t & (stride - 1));
            const int hi_i = lo_i + stride;
            const bool dirDesc = ((lo_i & size) == 0);
            const float va = bs[lo_i], vb = bs[hi_i];
            const int ia = bi[lo_i], ib = bi[hi_i];
            const bool aB = (va > vb) || (va == vb && ia < ib);
            if (aB != dirDesc) {
                bs[lo_i] = vb; bs[hi_i] = va;
                bi[lo_i] = ib; bi[hi_i] = ia;
            }
        }
    }
    __syncthreads();
    #pragma unroll
    for (int h = 0; h < 2; ++h) {
        const int s = t + h * 64;
        if (s < needed) {
            const int li = bi[s];
            const int gi = g * NPG + li;
            out[OUT_PERM   + g * KSEL + lo + s] = (float)gi;
            out[OUT_SCORES + g * KSEL + lo + s] = bs[s];
            atomicOr(&keep_bits[gi >> 5], 1u << (gi & 31));
        }
    }
}

// ---------- Kernel 5: gather x_pooled (parallel: 4 rows/block, 16384 blocks) ----------
__global__ __launch_bounds__(256)
void k_gather(const float* __restrict__ x, const float* __restrict__ perm_f,
              float* __restrict__ out_x)
{
    const int row  = blockIdx.x * 4 + (threadIdx.x >> 6);
    const int lane = threadIdx.x & 63;
    const int pi = (int)perm_f[row];
    const float4* src = (const float4*)&x[(size_t)pi * CH];
    float4* dst = (float4*)&out_x[(size_t)row * CH];
    dst[lane] = src[lane];
}

// ---------- Kernel 6: per-block kept-edge counts + fill our -1 slab ----------
__global__ __launch_bounds__(256)
void k_edgecount(const int* __restrict__ ei, const unsigned int* __restrict__ keep_bits,
                 int* __restrict__ counts, float* __restrict__ out_edge)
{
    const int t = threadIdx.x;
    const float4 neg = make_float4(-1.f, -1.f, -1.f, -1.f);
    #pragma unroll
    for (int q = 0; q < 4; ++q) {
        ((float4*)out_edge)[(size_t)blockIdx.x * 1024 + q * 256 + t] = neg;
        ((float4*)(out_edge + NE))[(size_t)blockIdx.x * 1024 + q * 256 + t] = neg;
    }

    const size_t base = (size_t)blockIdx.x * 4096 + (size_t)t * 16;
    const int* rowp = ei;
    const int* colp = ei + NE;
    int rv[16], cv[16];
    #pragma unroll
    for (int q = 0; q < 4; ++q) {
        int4 r4 = *(const int4*)&rowp[base + q * 4];
        int4 c4 = *(const int4*)&colp[base + q * 4];
        rv[q*4+0]=r4.x; rv[q*4+1]=r4.y; rv[q*4+2]=r4.z; rv[q*4+3]=r4.w;
        cv[q*4+0]=c4.x; cv[q*4+1]=c4.y; cv[q*4+2]=c4.z; cv[q*4+3]=c4.w;
    }
    int cnt = 0;
    #pragma unroll
    for (int q = 0; q < 16; ++q)
        cnt += (int)((keep_bits[rv[q] >> 5] >> (rv[q] & 31)) &
                     (keep_bits[cv[q] >> 5] >> (cv[q] & 31)) & 1u);

    #pragma unroll
    for (int off = 1; off < 64; off <<= 1) cnt += __shfl_xor(cnt, off, 64);
    __shared__ int wsum[4];
    if ((t & 63) == 0) wsum[t >> 6] = cnt;
    __syncthreads();
    if (t == 0) counts[blockIdx.x] = wsum[0] + wsum[1] + wsum[2] + wsum[3];
}

// ---------- Kernel 7: stable scatter of kept edges (scan fused in) ----------
__global__ __launch_bounds__(256)
void k_scatter(const int* __restrict__ ei, const unsigned int* __restrict__ keep_bits,
               const int* __restrict__ counts, float* __restrict__ out_edge)
{
    const int t = threadIdx.x;
    const int lane = t & 63, w = t >> 6;

    // inline exclusive scan: base = sum(counts[0..bid)) — counts is 4 KB, L2-hot
    int pre = 0;
    for (int i = t; i < blockIdx.x; i += 256) pre += counts[i];
    #pragma unroll
    for (int off = 1; off < 64; off <<= 1) pre += __shfl_xor(pre, off, 64);
    __shared__ int wpre[4];
    if (lane == 0) wpre[w] = pre;

    const size_t base = (size_t)blockIdx.x * 4096 + (size_t)t * 16;
    const int* rowp = ei;
    const int* colp = ei + NE;
    int rv[16], cv[16];
    #pragma unroll
    for (int q = 0; q < 4; ++q) {
        int4 r4 = *(const int4*)&rowp[base + q * 4];
        int4 c4 = *(const int4*)&colp[base + q * 4];
        rv[q*4+0]=r4.x; rv[q*4+1]=r4.y; rv[q*4+2]=r4.z; rv[q*4+3]=r4.w;
        cv[q*4+0]=c4.x; cv[q*4+1]=c4.y; cv[q*4+2]=c4.z; cv[q*4+3]=c4.w;
    }
    unsigned m = 0; int cnt = 0;
    #pragma unroll
    for (int q = 0; q < 16; ++q) {
        const bool kk = ((keep_bits[rv[q] >> 5] >> (rv[q] & 31)) &
                         (keep_bits[cv[q] >> 5] >> (cv[q] & 31)) & 1u) != 0u;
        m |= ((unsigned)kk) << q;
        cnt += (int)kk;
    }
    int incl = cnt;
    #pragma unroll
    for (int off = 1; off < 64; off <<= 1) {
        int v = __shfl_up(incl, off, 64);
        if (lane >= off) incl += v;
    }
    __shared__ int wtot[4];
    if (lane == 63) wtot[w] = incl;
    __syncthreads();
    const int blk_base = wpre[0] + wpre[1] + wpre[2] + wpre[3];
    int wbase = 0;
    for (int i = 0; i < w; ++i) wbase += wtot[i];
    int pos = blk_base + wbase + (incl - cnt);
    #pragma unroll
    for (int q = 0; q < 16; ++q) {
        if (m & (1u << q)) {
            out_edge[pos]      = (float)rv[q];
            out_edge[NE + pos] = (float)cv[q];
            ++pos;
        }
    }
}

extern "C" void kernel_launch(void* const* d_in, const int* in_sizes, int n_in,
                              void* d_out, int out_size, void* d_ws, size_t ws_size,
                              hipStream_t stream)
{
    const float* x  = (const float*)d_in[0];
    const int*   ei = (const int*)d_in[1];
    const float* W1 = (const float*)d_in[3];
    const float* b1 = (const float*)d_in[4];
    const float* W2 = (const float*)d_in[5];
    const float* b2 = (const float*)d_in[6];

    float* out = (float*)d_out;
    char*  ws  = (char*)d_ws;
    float*          scores    = (float*)(ws + WS_SCORES);
    unsigned int*   keep_bits = (unsigned int*)(ws + WS_KEEP);
    int*            counts    = (int*)(ws + WS_COUNTS);
    unsigned short* W1b       = (unsigned short*)(ws + WS_BFRAG);
    int*            band_idx  = (int*)(ws + WS_BIDX);
    float*          band_sc   = (float*)(ws + WS_BSCORE);
    int*            band_n    = (int*)(ws + WS_BN);
    int*            band_lo   = (int*)(ws + WS_BLO);

    k_cvtW<<<32, 256, 0, stream>>>(W1, W1b, keep_bits);
    k_mfma_scores<<<NN / 64, 256, 0, stream>>>(x, W1b, b1, W2, b2, scores);
    k_topk<<<NG, 256, 0, stream>>>(scores, out, keep_bits, band_idx, band_n, band_lo);
    k_rescore<<<NG * (CAP / 32), 256, 0, stream>>>(x, W1, b1, W2, b2, band_idx, band_n, band_sc);
    k_bandsel<<<NG, 64, 0, stream>>>(band_sc, band_idx, band_n, band_lo, out, keep_bits);
    k_gather<<<(NG * KSEL) / 4, 256, 0, stream>>>(x, out + OUT_PERM, out + OUT_X);
    k_edgecount<<<NE / 4096, 256, 0, stream>>>(ei, keep_bits, counts, out + OUT_EDGE);
    k_scatter<<<NE / 4096, 256, 0, stream>>>(ei, keep_bits, counts, out + OUT_EDGE);
}

// Round 18
// 156.320 us; speedup vs baseline: 1.1380x; 1.0035x over previous
//
#include <hip/hip_runtime.h>
#include <hip/hip_bf16.h>

// Problem constants (static graph layout from the reference)
#define NG 128          // graphs
#define NPG 1024        // nodes per graph
#define NN (NG * NPG)   // 131072 nodes
#define NE (NN * 32)    // 4194304 edges
#define CH 256          // channels
#define KSEL 512        // top-k per graph

#define CAP 128         // band capacity per graph
#define EPS 0.02f       // bf16-score uncertainty band half-width

// Output layout (all float32, concatenated flat in return order)
#define OUT_X      0
#define OUT_EDGE   16777216
#define OUT_BATCH  25165824
#define OUT_PERM   25231360
#define OUT_SCORES 25296896

// Workspace layout (bytes)
#define WS_SCORES  0           // 131072 f32
#define WS_KEEP    524288      // bit-packed keep: 16 KB
#define WS_COUNTS  540672      // 1024 int
#define WS_BFRAG   548864      // W1 bf16 fragment-linear: 128 KB
#define WS_BIDX    679936      // band local idx: NG*CAP int = 64 KB
#define WS_BSCORE  745472      // band fp32 scores: 64 KB
#define WS_BN      811008      // band_n: NG int
#define WS_BLO     811520      // band_lo: NG int

typedef __attribute__((ext_vector_type(8))) short bf16x8;
typedef __attribute__((ext_vector_type(4))) float f32x4;

__device__ __forceinline__ unsigned short f2bf(float f) {
    unsigned int b = __float_as_uint(f);
    return (unsigned short)((b + 0x7fffu + ((b >> 16) & 1u)) >> 16);  // RNE
}

// pack two fp32 -> one u32 of 2xbf16 via HW v_cvt_pk_bf16_f32 (RNE == f2bf)
__device__ __forceinline__ unsigned int cvt2bf(float lo, float hi) {
    union { __hip_bfloat162 h; unsigned int u; } c;
    c.h = __float22bfloat162_rn(make_float2(lo, hi));
    return c.u;
}

// fast tanh for the APPROX path only: 1 - 2/(exp(2h)+1); saturates, no NaN.
__device__ __forceinline__ float tanh_fast(float h) {
    const float e = __expf(2.0f * h);
    return 1.0f - 2.0f / (e + 1.0f);
}

// ---------- Kernel 0: pack W1 -> bf16 fragment-linear; also zero keep_bits ----------
__global__ __launch_bounds__(256)
void k_cvtW(const float* __restrict__ W1, unsigned short* __restrict__ W1b,
            unsigned int* __restrict__ keep_bits)
{
    const int t = blockIdx.x * 256 + threadIdx.x;   // 0..8191
    if (t < NN / 32) keep_bits[t] = 0u;             // 4096 words
    const int s    = t >> 10;
    const int rem  = t & 1023;
    const int n    = rem >> 6;
    const int lane = rem & 63;
    const int kbase = s * 32 + (lane >> 4) * 8;
    const int col   = n * 16 + (lane & 15);
    unsigned short u[8];
    #pragma unroll
    for (int j = 0; j < 8; ++j)
        u[j] = f2bf(W1[(size_t)(kbase + j) * CH + col]);
    uint4 v;
    v.x = u[0] | ((unsigned int)u[1] << 16);
    v.y = u[2] | ((unsigned int)u[3] << 16);
    v.z = u[4] | ((unsigned int)u[5] << 16);
    v.w = u[6] | ((unsigned int)u[7] << 16);
    *(uint4*)&W1b[(size_t)t * 8] = v;
}

// ---------- Kernel 1: approx scores via bf16 MFMA (R14/R16 best) ----------
__global__ __launch_bounds__(256, 4)
void k_mfma_scores(const float* __restrict__ x, const unsigned short* __restrict__ W1b,
                   const float* __restrict__ b1, const float* __restrict__ W2,
                   const float* __restrict__ b2, float* __restrict__ scores)
{
    __shared__ __align__(16) short As[64 * 256];   // 32 KB row-major bf16, swizzled
    __shared__ float epi[4][64];

    const int tid = threadIdx.x;
    const int w_  = tid >> 6;
    const int l   = tid & 63;
    const int n0  = blockIdx.x * 64;

    // ---- stage x tile: fp32 coalesced read -> bf16 row-major LDS (swizzled) ----
    #pragma unroll
    for (int it = 0; it < 16; ++it) {
        const int flat = it * 1024 + tid * 4;
        const int row = flat >> 8;
        const int c   = flat & 255;            // multiple of 4
        const float4 v = *(const float4*)&x[(size_t)(n0 + row) * CH + c];
        uint2 p;
        p.x = cvt2bf(v.x, v.y);
        p.y = cvt2bf(v.z, v.w);
        const int byte = (row * 512 + c * 2) ^ ((row & 7) << 4);
        *(uint2*)((char*)As + byte) = p;
    }
    __syncthreads();

    f32x4 acc[4][4];
    #pragma unroll
    for (int m = 0; m < 4; ++m)
        #pragma unroll
        for (int n = 0; n < 4; ++n)
            acc[m][n] = (f32x4){0.f, 0.f, 0.f, 0.f};

    // B-frag double buffer (all indices compile-time per unrolled iteration)
    const unsigned short* Wl = W1b + l * 8;
    bf16x8 bc[4], bn[4];
    #pragma unroll
    for (int ni = 0; ni < 4; ++ni)
        bc[ni] = *(const bf16x8*)&Wl[(size_t)(w_ * 4 + ni) * 512];

    #pragma unroll
    for (int s = 0; s < 8; ++s) {
        if (s < 7) {
            #pragma unroll
            for (int ni = 0; ni < 4; ++ni)
                bn[ni] = *(const bf16x8*)&Wl[(size_t)((s + 1) * 16 + w_ * 4 + ni) * 512];
        }
        // A-frags: lane l -> row m*16+(l&15), k = s*32 + (l>>4)*8 + j
        bf16x8 a[4];
        #pragma unroll
        for (int m = 0; m < 4; ++m) {
            const int row  = m * 16 + (l & 15);
            const int byte = (row * 512 + s * 64 + ((l >> 4) * 16)) ^ ((l & 7) << 4);
            a[m] = *(const bf16x8*)((const char*)As + byte);
        }
        #pragma unroll
        for (int ni = 0; ni < 4; ++ni)
            #pragma unroll
            for (int m = 0; m < 4; ++m)
                acc[m][ni] = __builtin_amdgcn_mfma_f32_16x16x32_bf16(a[m], bc[ni], acc[m][ni], 0, 0, 0);
        #pragma unroll
        for (int ni = 0; ni < 4; ++ni) bc[ni] = bn[ni];
    }

    // ---- epilogue: h = acc + b1[col]; t = tanh_fast(h); row sums of t*W2 ----
    float part[16];   // [m*4 + r]: node = m*16 + (l>>4)*4 + r
    #pragma unroll
    for (int i = 0; i < 16; ++i) part[i] = 0.f;
    #pragma unroll
    for (int ni = 0; ni < 4; ++ni) {
        const int col = w_ * 64 + ni * 16 + (l & 15);
        const float b1c = b1[col];
        const float w2c = W2[col];
        #pragma unroll
        for (int m = 0; m < 4; ++m)
            #pragma unroll
            for (int r = 0; r < 4; ++r)
                part[m * 4 + r] += tanh_fast(acc[m][ni][r] + b1c) * w2c;
    }
    #pragma unroll
    for (int off = 1; off < 16; off <<= 1)
        #pragma unroll
        for (int i = 0; i < 16; ++i)
            part[i] += __shfl_xor(part[i], off, 64);

    if ((l & 15) == 0) {
        const int gq = l >> 4;
        #pragma unroll
        for (int m = 0; m < 4; ++m)
            #pragma unroll
            for (int r = 0; r < 4; ++r)
                epi[w_][m * 16 + gq * 4 + r] = part[m * 4 + r];
    }
    __syncthreads();
    if (tid < 64)
        scores[n0 + tid] = epi[0][tid] + epi[1][tid] + epi[2][tid] + epi[3][tid] + b2[0];
}

// ---------- Kernel 2: radix-select top-512 threshold + certain/band classification ----------
__global__ __launch_bounds__(256)
void k_topk(const float* __restrict__ scores, float* __restrict__ out,
            unsigned int* __restrict__ keep_bits, int* __restrict__ band_idx,
            int* __restrict__ band_n, int* __restrict__ band_lo)
{
    __shared__ float    sf[1024];
    __shared__ unsigned uk[1024];
    __shared__ int      hist[256];
    __shared__ int      cge[256];
    __shared__ unsigned s_prefix;
    __shared__ int      s_rank;
    __shared__ int      wtot[4];

    const int g = blockIdx.x;
    const int t = threadIdx.x;

    #pragma unroll
    for (int h = 0; h < 4; ++h) {
        const int i = h * 256 + t;
        const float f = scores[g * NPG + i];
        sf[i] = f;
        const unsigned b = __float_as_uint(f);
        uk[i] = (b & 0x80000000u) ? ~b : (b | 0x80000000u);   // monotone: bigger u = bigger f
    }
    if (t == 0) { s_prefix = 0u; s_rank = KSEL; }
    __syncthreads();

    const unsigned pmaskv[4] = {0u, 0xFF000000u, 0xFFFF0000u, 0xFFFFFF00u};
    #pragma unroll
    for (int pass = 0; pass < 4; ++pass) {
        const int shift = 24 - pass * 8;
        hist[t] = 0;
        __syncthreads();
        const unsigned pm  = pmaskv[pass];
        const unsigned pfx = s_prefix;
        #pragma unroll
        for (int h = 0; h < 4; ++h) {
            const unsigned u = uk[h * 256 + t];
            if ((u & pm) == pfx) atomicAdd(&hist[(u >> shift) & 255], 1);
        }
        __syncthreads();
        cge[t] = hist[t];
        __syncthreads();
        #pragma unroll
        for (int off = 1; off < 256; off <<= 1) {        // suffix sums: cge[b] = #(byte >= b)
            const int v = (t + off < 256) ? cge[t + off] : 0;
            __syncthreads();
            cge[t] += v;
            __syncthreads();
        }
        const int r = s_rank;
        const int above = (t == 255) ? 0 : cge[t + 1];
        if (cge[t] >= r && above < r) {                  // exactly one thread matches
            s_prefix = pfx | ((unsigned)t << shift);
            s_rank   = r - above;
        }
        __syncthreads();
    }

    const unsigned u512 = s_prefix;                      // full rank-512 key
    const unsigned fb = (u512 & 0x80000000u) ? (u512 & 0x7FFFFFFFu) : ~u512;
    const float tau = __uint_as_float(fb);

    // deterministic classification + stable compaction (node li = t*4+j)
    bool cert[4], bnd[4];
    int myc = 0, myb = 0;
    #pragma unroll
    for (int j = 0; j < 4; ++j) {
        const float f = sf[t * 4 + j];
        cert[j] = (f > tau + EPS);
        bnd[j]  = (!cert[j]) && (f >= tau - EPS);
        myc += cert[j] ? 1 : 0;
        myb += bnd[j] ? 1 : 0;
    }
    const int pack = (myc << 16) | myb;
    const int lane = t & 63, w = t >> 6;
    int incl = pack;
    #pragma unroll
    for (int off = 1; off < 64; off <<= 1) {
        const int v = __shfl_up(incl, off, 64);
        if (lane >= off) incl += v;
    }
    if (lane == 63) wtot[w] = incl;
    __syncthreads();
    int wbase = 0;
    for (int i = 0; i < w; ++i) wbase += wtot[i];
    const int excl = wbase + incl - pack;
    int cpos = excl >> 16;
    int bpos = excl & 0xFFFF;
    const int total = wtot[0] + wtot[1] + wtot[2] + wtot[3];

    #pragma unroll
    for (int j = 0; j < 4; ++j) {
        const int li = t * 4 + j;
        if (cert[j]) {
            const int gi = g * NPG + li;
            out[OUT_PERM   + g * KSEL + cpos] = (float)gi;
            out[OUT_SCORES + g * KSEL + cpos] = sf[li];
            atomicOr(&keep_bits[gi >> 5], 1u << (gi & 31));
            ++cpos;
        } else if (bnd[j]) {
            if (bpos < CAP) band_idx[g * CAP + bpos] = li;
            ++bpos;
        }
    }
    out[OUT_BATCH + g * KSEL + t]       = (float)g;
    out[OUT_BATCH + g * KSEL + t + 256] = (float)g;
    if (t == 0) {
        band_lo[g] = (total >> 16);
        band_n[g]  = min(total & 0xFFFF, CAP);
    }
}

// ---------- Kernel 3: exact fp32 rescore of band nodes (R11 block version) ----------
__global__ __launch_bounds__(256, 2)
void k_rescore(const float* __restrict__ x, const float* __restrict__ W1,
               const float* __restrict__ b1, const float* __restrict__ W2,
               const float* __restrict__ b2, const int* __restrict__ band_idx,
               const int* __restrict__ band_n, float* __restrict__ band_scores)
{
    const int g = blockIdx.x >> 2;
    const int c0 = (blockIdx.x & 3) * 32;
    if (band_n[g] <= c0) return;   // uniform early-exit (no barriers crossed)

    __shared__ __align__(16) float W1s[16][CH];
    __shared__ __align__(16) float Xs[32][16];

    const int tid = threadIdx.x;
    const int w_  = tid >> 6;
    const int l   = tid & 63;

    int iv = 0;
    if (w_ < 2) iv = band_idx[g * CAP + c0 + w_ * 16 + (l >> 2)] & 1023;
    const float* xg = x + ((size_t)g * NPG + iv) * CH;

    const float4 b1v = *(const float4*)&b1[l * 4];
    float acc[8][4];
    #pragma unroll
    for (int n = 0; n < 8; ++n) {
        acc[n][0] = b1v.x; acc[n][1] = b1v.y; acc[n][2] = b1v.z; acc[n][3] = b1v.w;
    }

    for (int kc = 0; kc < 16; ++kc) {
        __syncthreads();
        #pragma unroll
        for (int it = 0; it < 4; ++it) {
            const float* gp = W1 + (size_t)kc * (16 * CH) + (w_ * 4 + it) * CH + l * 4;
            float* lb = &W1s[0][0] + (w_ * 4 + it) * CH;
            __builtin_amdgcn_global_load_lds(
                (const __attribute__((address_space(1))) void*)gp,
                (__attribute__((address_space(3))) void*)lb, 16, 0, 0);
        }
        if (w_ < 2) {
            const float* gp = xg + kc * 16 + (l & 3) * 4;
            float* lb = &Xs[0][0] + w_ * 256;
            __builtin_amdgcn_global_load_lds(
                (const __attribute__((address_space(1))) void*)gp,
                (__attribute__((address_space(3))) void*)lb, 16, 0, 0);
        }
        __syncthreads();

        #pragma unroll
        for (int kq = 0; kq < 4; ++kq) {
            const int k4 = kq * 4;
            const float4 wv0 = *(const float4*)&W1s[k4 + 0][l * 4];
            const float4 wv1 = *(const float4*)&W1s[k4 + 1][l * 4];
            const float4 wv2 = *(const float4*)&W1s[k4 + 2][l * 4];
            const float4 wv3 = *(const float4*)&W1s[k4 + 3][l * 4];
            #pragma unroll
            for (int n = 0; n < 8; ++n) {
                const float4 xv = *(const float4*)&Xs[w_ * 8 + n][k4];
                acc[n][0] = fmaf(xv.x, wv0.x, acc[n][0]);
                acc[n][1] = fmaf(xv.x, wv0.y, acc[n][1]);
                acc[n][2] = fmaf(xv.x, wv0.z, acc[n][2]);
                acc[n][3] = fmaf(xv.x, wv0.w, acc[n][3]);
                acc[n][0] = fmaf(xv.y, wv1.x, acc[n][0]);
                acc[n][1] = fmaf(xv.y, wv1.y, acc[n][1]);
                acc[n][2] = fmaf(xv.y, wv1.z, acc[n][2]);
                acc[n][3] = fmaf(xv.y, wv1.w, acc[n][3]);
                acc[n][0] = fmaf(xv.z, wv2.x, acc[n][0]);
                acc[n][1] = fmaf(xv.z, wv2.y, acc[n][1]);
                acc[n][2] = fmaf(xv.z, wv2.z, acc[n][2]);
                acc[n][3] = fmaf(xv.z, wv2.w, acc[n][3]);
                acc[n][0] = fmaf(xv.w, wv3.x, acc[n][0]);
                acc[n][1] = fmaf(xv.w, wv3.y, acc[n][1]);
                acc[n][2] = fmaf(xv.w, wv3.z, acc[n][2]);
                acc[n][3] = fmaf(xv.w, wv3.w, acc[n][3]);
            }
        }
    }

    const float4 w2v = *(const float4*)&W2[l * 4];
    const float  bb  = b2[0];
    float s_[8];
    #pragma unroll
    for (int n = 0; n < 8; ++n) {
        s_[n] = tanhf(acc[n][0]) * w2v.x + tanhf(acc[n][1]) * w2v.y
              + tanhf(acc[n][2]) * w2v.z + tanhf(acc[n][3]) * w2v.w;
    }
    #pragma unroll
    for (int off = 1; off < 64; off <<= 1)
        #pragma unroll
        for (int n = 0; n < 8; ++n)
            s_[n] += __shfl_xor(s_[n], off, 64);

    if (l == 0) {
        #pragma unroll
        for (int n = 0; n < 8; ++n)
            band_scores[g * CAP + c0 + w_ * 8 + n] = s_[n] + bb;
    }
}

// ---------- Kernel 4: select top-(512-lo) of band by fp32 score ----------
__global__ __launch_bounds__(64)
void k_bandsel(const float* __restrict__ band_scores, const int* __restrict__ band_idx,
               const int* __restrict__ band_n, const int* __restrict__ band_lo,
               float* __restrict__ out, unsigned int* __restrict__ keep_bits)
{
    __shared__ float bs[CAP];
    __shared__ int   bi[CAP];
    const int g = blockIdx.x;
    const int t = threadIdx.x;
    const int n  = band_n[g];
    const int lo = band_lo[g];
    int needed = KSEL - lo;
    if (needed > n) needed = n;

    #pragma unroll
    for (int h = 0; h < 2; ++h) {
        const int q = t + h * 64;
        const bool valid = q < n;
        bs[q] = valid ? band_scores[g * CAP + q] : -3.402823466e+38f;
        bi[q] = valid ? band_idx[g * CAP + q] : (NPG + q);
    }
    __syncthreads();
    for (int size = 2; size <= CAP; size <<= 1) {
        for (int stride = size >> 1; stride > 0; stride >>= 1) {
            __syncthreads();
            const int lo_i = ((t & ~(stride - 1)) << 1) | (t & (stride - 1));
            const int hi_i = lo_i + stride;
            const bool dirDesc = ((lo_i & size) == 0);
            const float va = bs[lo_i], vb = bs[hi_i];
            const int ia = bi[lo_i], ib = bi[hi_i];
            const bool aB = (va > vb) || (va == vb && ia < ib);
            if (aB != dirDesc) {
                bs[lo_i] = vb; bs[hi_i] = va;
                bi[lo_i] = ib; bi[hi_i] = ia;
            }
        }
    }
    __syncthreads();
    #pragma unroll
    for (int h = 0; h < 2; ++h) {
        const int s = t + h * 64;
        if (s < needed) {
            const int li = bi[s];
            const int gi = g * NPG + li;
            out[OUT_PERM   + g * KSEL + lo + s] = (float)gi;
            out[OUT_SCORES + g * KSEL + lo + s] = bs[s];
            atomicOr(&keep_bits[gi >> 5], 1u << (gi & 31));
        }
    }
}

// ---------- Kernel 5: gather x_pooled (parallel: 4 rows/block, 16384 blocks) ----------
__global__ __launch_bounds__(256)
void k_gather(const float* __restrict__ x, const float* __restrict__ perm_f,
              float* __restrict__ out_x)
{
    const int row  = blockIdx.x * 4 + (threadIdx.x >> 6);
    const int lane = threadIdx.x & 63;
    const int pi = (int)perm_f[row];
    const float4* src = (const float4*)&x[(size_t)pi * CH];
    float4* dst = (float4*)&out_x[(size_t)row * CH];
    dst[lane] = src[lane];
}

// ---------- Kernel 6: per-block kept-edge counts + fill our -1 slab ----------
__global__ __launch_bounds__(256)
void k_edgecount(const int* __restrict__ ei, const unsigned int* __restrict__ keep_bits,
                 int* __restrict__ counts, float* __restrict__ out_edge)
{
    const int t = threadIdx.x;
    const float4 neg = make_float4(-1.f, -1.f, -1.f, -1.f);
    #pragma unroll
    for (int q = 0; q < 4; ++q) {
        ((float4*)out_edge)[(size_t)blockIdx.x * 1024 + q * 256 + t] = neg;
        ((float4*)(out_edge + NE))[(size_t)blockIdx.x * 1024 + q * 256 + t] = neg;
    }

    const size_t base = (size_t)blockIdx.x * 4096 + (size_t)t * 16;
    const int* rowp = ei;
    const int* colp = ei + NE;
    int rv[16], cv[16];
    #pragma unroll
    for (int q = 0; q < 4; ++q) {
        int4 r4 = *(const int4*)&rowp[base + q * 4];
        int4 c4 = *(const int4*)&colp[base + q * 4];
        rv[q*4+0]=r4.x; rv[q*4+1]=r4.y; rv[q*4+2]=r4.z; rv[q*4+3]=r4.w;
        cv[q*4+0]=c4.x; cv[q*4+1]=c4.y; cv[q*4+2]=c4.z; cv[q*4+3]=c4.w;
    }
    int cnt = 0;
    #pragma unroll
    for (int q = 0; q < 16; ++q)
        cnt += (int)((keep_bits[rv[q] >> 5] >> (rv[q] & 31)) &
                     (keep_bits[cv[q] >> 5] >> (cv[q] & 31)) & 1u);

    #pragma unroll
    for (int off = 1; off < 64; off <<= 1) cnt += __shfl_xor(cnt, off, 64);
    __shared__ int wsum[4];
    if ((t & 63) == 0) wsum[t >> 6] = cnt;
    __syncthreads();
    if (t == 0) counts[blockIdx.x] = wsum[0] + wsum[1] + wsum[2] + wsum[3];
}

// ---------- Kernel 7: stable scatter of kept edges (scan fused in) ----------
__global__ __launch_bounds__(256)
void k_scatter(const int* __restrict__ ei, const unsigned int* __restrict__ keep_bits,
               const int* __restrict__ counts, float* __restrict__ out_edge)
{
    const int t = threadIdx.x;
    const int lane = t & 63, w = t >> 6;

    // inline exclusive scan: base = sum(counts[0..bid)) — counts is 4 KB, L2-hot
    int pre = 0;
    for (int i = t; i < blockIdx.x; i += 256) pre += counts[i];
    #pragma unroll
    for (int off = 1; off < 64; off <<= 1) pre += __shfl_xor(pre, off, 64);
    __shared__ int wpre[4];
    if (lane == 0) wpre[w] = pre;

    const size_t base = (size_t)blockIdx.x * 4096 + (size_t)t * 16;
    const int* rowp = ei;
    const int* colp = ei + NE;
    int rv[16], cv[16];
    #pragma unroll
    for (int q = 0; q < 4; ++q) {
        int4 r4 = *(const int4*)&rowp[base + q * 4];
        int4 c4 = *(const int4*)&colp[base + q * 4];
        rv[q*4+0]=r4.x; rv[q*4+1]=r4.y; rv[q*4+2]=r4.z; rv[q*4+3]=r4.w;
        cv[q*4+0]=c4.x; cv[q*4+1]=c4.y; cv[q*4+2]=c4.z; cv[q*4+3]=c4.w;
    }
    unsigned m = 0; int cnt = 0;
    #pragma unroll
    for (int q = 0; q < 16; ++q) {
        const bool kk = ((keep_bits[rv[q] >> 5] >> (rv[q] & 31)) &
                         (keep_bits[cv[q] >> 5] >> (cv[q] & 31)) & 1u) != 0u;
        m |= ((unsigned)kk) << q;
        cnt += (int)kk;
    }
    int incl = cnt;
    #pragma unroll
    for (int off = 1; off < 64; off <<= 1) {
        int v = __shfl_up(incl, off, 64);
        if (lane >= off) incl += v;
    }
    __shared__ int wtot[4];
    if (lane == 63) wtot[w] = incl;
    __syncthreads();
    const int blk_base = wpre[0] + wpre[1] + wpre[2] + wpre[3];
    int wbase = 0;
    for (int i = 0; i < w; ++i) wbase += wtot[i];
    int pos = blk_base + wbase + (incl - cnt);
    #pragma unroll
    for (int q = 0; q < 16; ++q) {
        if (m & (1u << q)) {
            out_edge[pos]      = (float)rv[q];
            out_edge[NE + pos] = (float)cv[q];
            ++pos;
        }
    }
}

extern "C" void kernel_launch(void* const* d_in, const int* in_sizes, int n_in,
                              void* d_out, int out_size, void* d_ws, size_t ws_size,
                              hipStream_t stream)
{
    const float* x  = (const float*)d_in[0];
    const int*   ei = (const int*)d_in[1];
    const float* W1 = (const float*)d_in[3];
    const float* b1 = (const float*)d_in[4];
    const float* W2 = (const float*)d_in[5];
    const float* b2 = (const float*)d_in[6];

    float* out = (float*)d_out;
    char*  ws  = (char*)d_ws;
    float*          scores    = (float*)(ws + WS_SCORES);
    unsigned int*   keep_bits = (unsigned int*)(ws + WS_KEEP);
    int*            counts    = (int*)(ws + WS_COUNTS);
    unsigned short* W1b       = (unsigned short*)(ws + WS_BFRAG);
    int*            band_idx  = (int*)(ws + WS_BIDX);
    float*          band_sc   = (float*)(ws + WS_BSCORE);
    int*            band_n    = (int*)(ws + WS_BN);
    int*            band_lo   = (int*)(ws + WS_BLO);

    k_cvtW<<<32, 256, 0, stream>>>(W1, W1b, keep_bits);
    k_mfma_scores<<<NN / 64, 256, 0, stream>>>(x, W1b, b1, W2, b2, scores);
    k_topk<<<NG, 256, 0, stream>>>(scores, out, keep_bits, band_idx, band_n, band_lo);
    k_rescore<<<NG * (CAP / 32), 256, 0, stream>>>(x, W1, b1, W2, b2, band_idx, band_n, band_sc);
    k_bandsel<<<NG, 64, 0, stream>>>(band_sc, band_idx, band_n, band_lo, out, keep_bits);
    k_gather<<<(NG * KSEL) / 4, 256, 0, stream>>>(x, out + OUT_PERM, out + OUT_X);
    k_edgecount<<<NE / 4096, 256, 0, stream>>>(ei, keep_bits, counts, out + OUT_EDGE);
    k_scatter<<<NE / 4096, 256, 0, stream>>>(ei, keep_bits, counts, out + OUT_EDGE);
}